// Round 1
// baseline (921.229 us; speedup 1.0000x reference)
//
#include <hip/hip_runtime.h>
#include <math.h>

// FNO spectral block: B=4, S=16, C=64, R=128, MODES=16
// n = b*16+s in [0,64); image id = n*64+c in [0,4096)
// Mode slots: kxi in [0,32): kx_eff = kxi<16 ? kxi : 96+kxi (i.e. 112..127); ky in [0,16)

#define TWO_PI_OVER_128 0.04908738521234052f

// ---------------- Stage 1: residual scatter + partial rfft2 ----------------
__global__ __launch_bounds__(256) void k1_fwd(const float* __restrict__ ref,
                                              const int* __restrict__ lu,
                                              float* __restrict__ out,
                                              float2* __restrict__ Xf) {
  __shared__ float2 tab[128];        // (cos, sin)(2*pi*t/128)
  __shared__ float2 A2[128 * 17];    // A[x][ky], padded stride 17
  const int bid = blockIdx.x;        // = n*64 + c
  const int n = bid >> 6;
  const int c = bid & 63;
  const int b = n >> 4, s = n & 15;
  const int tid = threadIdx.x;
  if (tid < 128) {
    float sv, cv;
    sincosf((float)tid * TWO_PI_OVER_128, &sv, &cv);
    tab[tid] = make_float2(cv, sv);
  }
  const float* img = ref + (size_t)bid * 16384;
  float* outimg = out + (size_t)(b * 64 + c) * 16384;
  // residual: out[b,c,p] = ref[b,s,c,p] where lookup[p]==s  (coalesced read, warms L2)
  for (int p = tid; p < 16384; p += 256) {
    float v = img[p];
    if (lu[p] == s) outimg[p] = v;
  }
  __syncthreads();
  // y-pass: A[x,ky] = sum_y img[x,y] e^{-2pi i ky y/128}, using y <-> 128-y symmetry
  {
    const int x = tid >> 1, h = tid & 1;   // h selects ky half (8 each)
    const float* row = img + x * 128;
    float ar[8], ai[8];
    const float v0 = row[0], v64 = row[64];
#pragma unroll
    for (int j = 0; j < 8; ++j) {
      ar[j] = v0 + ((j & 1) ? -v64 : v64);  // (-1)^ky, ky=8h+j -> parity of j
      ai[j] = 0.f;
    }
    for (int y = 1; y < 64; ++y) {
      const float a = row[y], bb = row[128 - y];
      const float sv = a + bb, dv = a - bb;
#pragma unroll
      for (int j = 0; j < 8; ++j) {
        const int ky = 8 * h + j;
        const float2 cs = tab[(ky * y) & 127];
        ar[j] = fmaf(sv, cs.x, ar[j]);
        ai[j] = fmaf(-dv, cs.y, ai[j]);
      }
    }
#pragma unroll
    for (int j = 0; j < 8; ++j) A2[x * 17 + 8 * h + j] = make_float2(ar[j], ai[j]);
  }
  __syncthreads();
  // x-pass: X[kx,ky] = sum_x A[x,ky] e^{-2pi i kx x/128}; two kx per thread
  {
    const int ky = tid & 15, kxi = tid >> 4;  // kxi 0..15
    const int kxB = 112 + kxi;
    float Ar = 0.f, Aim = 0.f, Br = 0.f, Bim = 0.f;
    for (int x = 0; x < 128; ++x) {
      const float2 a = A2[x * 17 + ky];
      const float2 cA = tab[(kxi * x) & 127];
      Ar  += a.x * cA.x + a.y * cA.y;
      Aim += a.y * cA.x - a.x * cA.y;
      const float2 cB = tab[(kxB * x) & 127];
      Br  += a.x * cB.x + a.y * cB.y;
      Bim += a.y * cB.x - a.x * cB.y;
    }
    float2* dst = Xf + (size_t)bid * 512;
    dst[kxi * 16 + ky] = make_float2(Ar, Aim);
    dst[(kxi + 16) * 16 + ky] = make_float2(Br, Bim);
  }
}

// ---------------- Stage 2: per-mode complex channel mix ----------------
// Y[(b,o)][m][s] = sum_c X[(b,s)][c][m] * W[c][o][m] * wsc, wsc = (ky?2:1)/16384
__global__ __launch_bounds__(256) void k2_mix(const float2* __restrict__ Xf,
                                              const float* __restrict__ w1r,
                                              const float* __restrict__ w1i,
                                              const float* __restrict__ w2r,
                                              const float* __restrict__ w2i,
                                              float2* __restrict__ Yf) {
  __shared__ float2 Xs[64 * 65];  // [n][c] padded
  __shared__ float2 Ws[64 * 65];  // [o][c] padded
  const int m = blockIdx.x;       // mode slot
  const int kxi = m >> 4, ky = m & 15;
  const int tid = threadIdx.x;
  const float wsc = (ky == 0 ? 1.f : 2.f) / 16384.f;
  const float* Wr = (kxi < 16) ? w1r : w2r;
  const float* Wi = (kxi < 16) ? w1i : w2i;
  const int kxl = kxi & 15;
  for (int i = 0; i < 16; ++i) {
    const int elem = i * 256 + tid;        // 0..4095
    const int nn = elem >> 6, cc = elem & 63;
    Xs[nn * 65 + cc] = Xf[(size_t)elem * 512 + m];
    const int o = elem & 63, c2 = elem >> 6;
    const size_t wofs = ((size_t)(c2 * 64 + o) * 16 + kxl) * 16 + ky;
    Ws[o * 65 + c2] = make_float2(Wr[wofs] * wsc, Wi[wofs] * wsc);
  }
  __syncthreads();
  const int g = tid >> 4, t = tid & 15;  // g = s-lane, t = o-lane
  float accr[4][4] = {};
  float acci[4][4] = {};
  for (int cc = 0; cc < 64; ++cc) {
    float2 xv[4], wv[4];
#pragma unroll
    for (int k = 0; k < 4; ++k) xv[k] = Xs[(g + 16 * k) * 65 + cc];
#pragma unroll
    for (int j = 0; j < 4; ++j) wv[j] = Ws[(t + 16 * j) * 65 + cc];
#pragma unroll
    for (int k = 0; k < 4; ++k)
#pragma unroll
      for (int j = 0; j < 4; ++j) {
        accr[k][j] += xv[k].x * wv[j].x - xv[k].y * wv[j].y;
        acci[k][j] += xv[k].x * wv[j].y + xv[k].y * wv[j].x;
      }
  }
  // n = g + 16k -> s = g, b = k ; o = t + 16j ; Yf[bo][m][s]
#pragma unroll
  for (int k = 0; k < 4; ++k)
#pragma unroll
    for (int j = 0; j < 4; ++j) {
      const int bo = k * 64 + t + 16 * j;
      Yf[(size_t)bo * 8192 + (size_t)m * 16 + g] = make_float2(accr[k][j], acci[k][j]);
    }
}

// ---------------- Stage 3: partial irfft2 + gather + accumulate ----------------
__global__ __launch_bounds__(512) void k3_inv(const float2* __restrict__ Yf,
                                              const int* __restrict__ lu,
                                              float* __restrict__ out) {
  __shared__ float2 Ys[512 * 17];   // [m][s] padded
  __shared__ float tbuf[16 * 138];  // t[s][x_l 0..3][ky], strides 138/34/2 (bank-spread)
  __shared__ float2 tab[128];
  const int bo = blockIdx.x >> 1;
  const int half = blockIdx.x & 1;
  const int tid = threadIdx.x;
  if (tid < 128) {
    float sv, cv;
    sincosf((float)tid * TWO_PI_OVER_128, &sv, &cv);
    tab[tid] = make_float2(cv, sv);
  }
  for (int i = 0; i < 16; ++i) {
    const int elem = i * 512 + tid;  // 0..8191, = m*16+s
    Ys[(elem >> 4) * 17 + (elem & 15)] = Yf[(size_t)bo * 8192 + elem];
  }
  __syncthreads();
  const int ky = tid & 15, xl = (tid >> 4) & 3, sg = tid >> 6;  // sg 0..7
  float* outb = out + (size_t)bo * 16384;
  for (int xb = half * 16; xb < half * 16 + 16; ++xb) {
    {
      const int x = xb * 4 + xl;
#pragma unroll
      for (int rep = 0; rep < 2; ++rep) {
        const int ss = sg + rep * 8;
        float tre = 0.f, tim = 0.f;
        for (int kxi = 0; kxi < 32; ++kxi) {
          const float2 Y = Ys[(kxi * 16 + ky) * 17 + ss];
          const int kxe = (kxi < 16) ? kxi : (96 + kxi);
          const float2 cs = tab[(kxe * x) & 127];
          tre += Y.x * cs.x - Y.y * cs.y;   // Re(Y e^{+i psi})
          tim += Y.x * cs.y + Y.y * cs.x;
        }
        tbuf[ss * 138 + xl * 34 + ky * 2] = tre;
        tbuf[ss * 138 + xl * 34 + ky * 2 + 1] = tim;
      }
    }
    __syncthreads();
    {
      const int xl2 = tid >> 7, y = tid & 127;
      const int p = (xb * 4 + xl2) * 128 + y;
      const int ssel = lu[p];
      const float res = outb[p];
      float acc = 0.f;
#pragma unroll
      for (int k2 = 0; k2 < 16; ++k2) {
        const float tre = tbuf[ssel * 138 + xl2 * 34 + k2 * 2];
        const float tim = tbuf[ssel * 138 + xl2 * 34 + k2 * 2 + 1];
        const float2 cs = tab[(k2 * y) & 127];
        acc += tre * cs.x - tim * cs.y;     // Re(t e^{+i phi}), weights folded in K2
      }
      outb[p] = res + acc;
    }
    __syncthreads();
  }
}

extern "C" void kernel_launch(void* const* d_in, const int* in_sizes, int n_in,
                              void* d_out, int out_size, void* d_ws, size_t ws_size,
                              hipStream_t stream) {
  const float* ref = (const float*)d_in[0];
  // d_in[1] = physical_coords (unused)
  const int* lu = (const int*)d_in[2];
  const float* w1r = (const float*)d_in[3];
  const float* w1i = (const float*)d_in[4];
  const float* w2r = (const float*)d_in[5];
  const float* w2i = (const float*)d_in[6];
  float* out = (float*)d_out;

  float2* Xf = (float2*)d_ws;                  // 4096 images * 512 modes * 8B = 16.78 MB
  float2* Yf = Xf + (size_t)4096 * 512;        // 256 bo * 8192 * 8B = 16.78 MB

  k1_fwd<<<4096, 256, 0, stream>>>(ref, lu, out, Xf);
  k2_mix<<<512, 256, 0, stream>>>(Xf, w1r, w1i, w2r, w2i, Yf);
  k3_inv<<<512, 512, 0, stream>>>(Yf, lu, out);
}

// Round 2
// 266.643 us; speedup vs baseline: 3.4549x; 3.4549x over previous
//
#include <hip/hip_runtime.h>
#include <math.h>

// FNO spectral block: B=4, S=16, C=64, R=128, MODES=16
// n = b*16+s in [0,64); image id bid = n*64+c in [0,4096)
// Mode slot m = kxi*16+ky, kxi in [0,32): kx_eff = kxi<16 ? kxi : 96+kxi; ky in [0,16)
// Intermediates stored as packed bf16 (re,im) pairs; compute in fp32.

#define TWO_PI_OVER_128 0.04908738521234052f

__device__ __forceinline__ unsigned pk(float a, float b) {
  unsigned ua = __float_as_uint(a), ub = __float_as_uint(b);
  ua = (ua + 0x7FFFu + ((ua >> 16) & 1u)) >> 16;
  ub = (ub + 0x7FFFu + ((ub >> 16) & 1u)) >> 16;
  return ua | (ub << 16);
}
__device__ __forceinline__ float2 upk(unsigned v) {
  return make_float2(__uint_as_float(v << 16), __uint_as_float(v & 0xFFFF0000u));
}

// ---------------- Weights transpose: w[c][o][kx][ky] -> Wt[m][o][c], wsc folded ---
__global__ __launch_bounds__(256) void ktw(const float* __restrict__ w1r,
                                           const float* __restrict__ w1i,
                                           const float* __restrict__ w2r,
                                           const float* __restrict__ w2i,
                                           unsigned* __restrict__ Wt) {
  __shared__ unsigned tile[64 * 65];
  const int o = blockIdx.x & 63, wsel = blockIdx.x >> 6;
  const float* Wr = wsel ? w2r : w1r;
  const float* Wi = wsel ? w2i : w1i;
  const int tid = threadIdx.x;
  for (int mc = 0; mc < 4; ++mc) {
    if (mc) __syncthreads();
    for (int i = 0; i < 16; ++i) {
      int idx = i * 256 + tid;           // 0..4095
      int c = idx >> 6, ml = idx & 63;
      int mh = mc * 64 + ml;             // m within half = kxl*16+ky
      float wsc = ((mh & 15) ? 2.f : 1.f) / 16384.f;
      size_t off = (size_t)(c * 64 + o) * 256 + mh;
      tile[c * 65 + ml] = pk(Wr[off] * wsc, Wi[off] * wsc);
    }
    __syncthreads();
    for (int i = 0; i < 16; ++i) {
      int idx = i * 256 + tid;
      int ml = idx >> 6, c = idx & 63;
      Wt[(size_t)(wsel * 256 + mc * 64 + ml) * 4096 + o * 64 + c] = tile[c * 65 + ml];
    }
  }
}

// ---------------- Stage 1: partial rfft2 (LDS-staged, rotation twiddles) ----------
__global__ __launch_bounds__(256) void k1_fwd(const float* __restrict__ ref,
                                              unsigned* __restrict__ Xf) {
  __shared__ float img[64 * 129];   // half image, row stride 129
  __shared__ float2 A2[128 * 17];   // A[x][ky]
  __shared__ float2 tab[128];
  const int bid = blockIdx.x;
  const int tid = threadIdx.x;
  if (tid < 128) {
    float sv, cv;
    sincosf((float)tid * TWO_PI_OVER_128, &sv, &cv);
    tab[tid] = make_float2(cv, sv);
  }
  const float* im = ref + (size_t)bid * 16384;
  const int xl = tid >> 2, h = tid & 3;  // y-pass: row xl, ky group 4h..4h+3

  for (int half = 0; half < 2; ++half) {
    __syncthreads();  // tab ready (half 0); img free for reuse (half 1)
    for (int i = 0; i < 8; ++i) {
      int e4 = i * 256 + tid;               // 0..2047 float4s in half
      int pl = e4 * 4;                      // local float index
      float4 v = *(const float4*)(im + half * 8192 + pl);
      float* d = img + (pl >> 7) * 129 + (pl & 127);
      d[0] = v.x; d[1] = v.y; d[2] = v.z; d[3] = v.w;
    }
    __syncthreads();
    // y-pass with y <-> 128-y symmetry, rotation twiddles
    const float* row = img + xl * 129;
    const float v0 = row[0], v64 = row[64];
    float ar[4], ai[4], cst[4], sst[4], cstp[4], sstp[4];
#pragma unroll
    for (int j = 0; j < 4; ++j) {
      ar[j] = v0 + ((j & 1) ? -v64 : v64);   // parity(ky)=parity(j), ky=4h+j
      ai[j] = 0.f;
      float2 t0 = tab[4 * h + j];            // angle ky*theta (state at y=1 = step)
      cst[j] = cstp[j] = t0.x;
      sst[j] = sstp[j] = t0.y;
    }
    for (int y = 1; y < 64; ++y) {
      const float a = row[y], bb = row[128 - y];
      const float sv = a + bb, dv = a - bb;
#pragma unroll
      for (int j = 0; j < 4; ++j) {
        ar[j] = fmaf(sv, cst[j], ar[j]);
        ai[j] = fmaf(-dv, sst[j], ai[j]);
        float nc = cst[j] * cstp[j] - sst[j] * sstp[j];
        float ns = sst[j] * cstp[j] + cst[j] * sstp[j];
        cst[j] = nc; sst[j] = ns;
      }
    }
#pragma unroll
    for (int j = 0; j < 4; ++j)
      A2[(half * 64 + xl) * 17 + 4 * h + j] = make_float2(ar[j], ai[j]);
  }
  __syncthreads();
  // S/D fold: A2[x] <- A[x]+A[128-x], A2[128-x] <- A[x]-A[128-x], x=1..63
  for (int t4 = 0; t4 < 4; ++t4) {
    int task = t4 * 256 + tid;
    if (task < 1008) {
      int x = 1 + (task >> 4), ky = task & 15;
      float2 P = A2[x * 17 + ky], Q = A2[(128 - x) * 17 + ky];
      A2[x * 17 + ky] = make_float2(P.x + Q.x, P.y + Q.y);
      A2[(128 - x) * 17 + ky] = make_float2(P.x - Q.x, P.y - Q.y);
    }
  }
  __syncthreads();
  // x-pass: X_k = A0 + (-1)^k A64 + sum_{x=1}^{63} (S cos - i D sin), k in {kxi, 112+kxi}
  {
    const int ky = tid & 15, kxi = tid >> 4;
    const float sg = (kxi & 1) ? -1.f : 1.f;
    const float2 a0 = A2[0 * 17 + ky], a64 = A2[64 * 17 + ky];
    float XAr = fmaf(sg, a64.x, a0.x), XAi = fmaf(sg, a64.y, a0.y);
    float XBr = XAr, XBi = XAi;
    const float2 sA0 = tab[kxi], sB0 = tab[112 + kxi];
    float cA = sA0.x, sA = sA0.y, cB = sB0.x, sB = sB0.y;
    for (int x = 1; x < 64; ++x) {
      const float2 S = A2[x * 17 + ky], D = A2[(128 - x) * 17 + ky];
      XAr = fmaf(S.x, cA, fmaf(D.y, sA, XAr));
      XAi = fmaf(S.y, cA, fmaf(-D.x, sA, XAi));
      XBr = fmaf(S.x, cB, fmaf(D.y, sB, XBr));
      XBi = fmaf(S.y, cB, fmaf(-D.x, sB, XBi));
      float nc = cA * sA0.x - sA * sA0.y, ns = sA * sA0.x + cA * sA0.y;
      cA = nc; sA = ns;
      nc = cB * sB0.x - sB * sB0.y; ns = sB * sB0.x + cB * sB0.y;
      cB = nc; sB = ns;
    }
    unsigned* dst = Xf + (size_t)bid * 512;
    dst[tid] = pk(XAr, XAi);          // m = kxi*16+ky = tid
    dst[tid + 256] = pk(XBr, XBi);    // m = (16+kxi)*16+ky
  }
}

// ---------------- Transpose Xf[bid][m] -> Xf2[m][bid] -------------------------
__global__ __launch_bounds__(256) void kt(const unsigned* __restrict__ Xf,
                                          unsigned* __restrict__ Xf2) {
  __shared__ unsigned tile[64 * 65];
  const int bm = blockIdx.x & 7, bn = blockIdx.x >> 3;
  const int tid = threadIdx.x;
  for (int i = 0; i < 16; ++i) {
    int idx = i * 256 + tid;
    int r = idx >> 6, cc = idx & 63;
    tile[r * 65 + cc] = Xf[(size_t)(bn * 64 + r) * 512 + bm * 64 + cc];
  }
  __syncthreads();
  for (int i = 0; i < 16; ++i) {
    int idx = i * 256 + tid;
    int r = idx >> 6, cc = idx & 63;
    Xf2[(size_t)(bm * 64 + r) * 4096 + bn * 64 + cc] = tile[cc * 65 + r];
  }
}

// ---------------- Stage 2: per-mode complex channel mix ------------------------
__global__ __launch_bounds__(256) void k2_mix(const unsigned* __restrict__ Xf2,
                                              const unsigned* __restrict__ Wt,
                                              unsigned* __restrict__ Yf) {
  __shared__ float2 Xs[64 * 65];  // [n][c]
  __shared__ float2 Ws[64 * 65];  // [o][c]
  const int m = blockIdx.x;
  const int tid = threadIdx.x;
  for (int i = 0; i < 16; ++i) {
    int e = i * 256 + tid;
    Xs[(e >> 6) * 65 + (e & 63)] = upk(Xf2[(size_t)m * 4096 + e]);
    Ws[(e >> 6) * 65 + (e & 63)] = upk(Wt[(size_t)m * 4096 + e]);
  }
  __syncthreads();
  const int g = tid >> 4, t = tid & 15;  // s-lane, o-lane
  float accr[4][4] = {}, acci[4][4] = {};
  for (int cc = 0; cc < 64; ++cc) {
    float2 xv[4], wv[4];
#pragma unroll
    for (int k = 0; k < 4; ++k) xv[k] = Xs[(g + 16 * k) * 65 + cc];
#pragma unroll
    for (int j = 0; j < 4; ++j) wv[j] = Ws[(t + 16 * j) * 65 + cc];
#pragma unroll
    for (int k = 0; k < 4; ++k)
#pragma unroll
      for (int j = 0; j < 4; ++j) {
        accr[k][j] += xv[k].x * wv[j].x - xv[k].y * wv[j].y;
        acci[k][j] += xv[k].x * wv[j].y + xv[k].y * wv[j].x;
      }
  }
  __syncthreads();
  unsigned* Os = (unsigned*)Xs;  // 256*17 uints = 17.4 KB, fits in Xs
#pragma unroll
  for (int k = 0; k < 4; ++k)
#pragma unroll
    for (int j = 0; j < 4; ++j) {
      int bo = k * 64 + t + 16 * j;   // b=k, o=t+16j, s=g
      Os[bo * 17 + g] = pk(accr[k][j], acci[k][j]);
    }
  __syncthreads();
  for (int i = 0; i < 16; ++i) {
    int e = i * 256 + tid;
    int bo = e >> 4, ss = e & 15;
    Yf[(size_t)bo * 8192 + m * 16 + ss] = Os[bo * 17 + ss];
  }
}

// ---------------- Stage 3: partial irfft2 + residual gather --------------------
__global__ __launch_bounds__(512) void k3_inv(const unsigned* __restrict__ Yf,
                                              const int* __restrict__ lu,
                                              const float* __restrict__ ref,
                                              float* __restrict__ out) {
  __shared__ float2 Ys[16 * 512];   // [s][m ^ s]  (XOR swizzle, conflict-free)
  __shared__ float tbuf[16 * 138];  // t[s][xl][ky] (re,im interleaved)
  __shared__ float2 tab[128];
  const int bo = blockIdx.x >> 1, half = blockIdx.x & 1;
  const int bq = bo >> 6, oq = bo & 63;
  const int tid = threadIdx.x;
  if (tid < 128) {
    float sv, cv;
    sincosf((float)tid * TWO_PI_OVER_128, &sv, &cv);
    tab[tid] = make_float2(cv, sv);
  }
  for (int i = 0; i < 16; ++i) {
    int e = i * 512 + tid;            // = m*16 + s
    int ss = e & 15, mm = e >> 4;
    Ys[ss * 512 + (mm ^ ss)] = upk(Yf[(size_t)bo * 8192 + e]);
  }
  __syncthreads();
  const int ky = tid & 15, xl = (tid >> 4) & 3, sg = tid >> 6;  // sg 0..7
  const int ss0 = sg, ss1 = sg + 8;
  float* outb = out + (size_t)bo * 16384;
  const float* refb = ref + (size_t)(bq * 16) * 64 * 16384 + (size_t)oq * 16384;

  for (int xb = half * 16; xb < half * 16 + 16; ++xb) {
    {
      const int x = xb * 4 + xl;
      const float2 stp = tab[x];                    // step e^{+i x theta}
      float c0 = 1.f, s0 = 0.f;
      float tre0 = 0.f, tim0 = 0.f, tre1 = 0.f, tim1 = 0.f;
#pragma unroll
      for (int kxi = 0; kxi < 32; ++kxi) {
        if (kxi == 16) {
          float2 st = tab[(112 * x) & 127];         // jump to kx=112
          c0 = st.x; s0 = st.y;
        }
        const int mb = kxi * 16 + ky;
        const float2 Y0 = Ys[ss0 * 512 + (mb ^ ss0)];
        const float2 Y1 = Ys[ss1 * 512 + (mb ^ ss1)];
        tre0 = fmaf(Y0.x, c0, fmaf(-Y0.y, s0, tre0));
        tim0 = fmaf(Y0.x, s0, fmaf(Y0.y, c0, tim0));
        tre1 = fmaf(Y1.x, c0, fmaf(-Y1.y, s0, tre1));
        tim1 = fmaf(Y1.x, s0, fmaf(Y1.y, c0, tim1));
        float nc = c0 * stp.x - s0 * stp.y, ns = s0 * stp.x + c0 * stp.y;
        c0 = nc; s0 = ns;
      }
      tbuf[ss0 * 138 + xl * 34 + ky * 2] = tre0;
      tbuf[ss0 * 138 + xl * 34 + ky * 2 + 1] = tim0;
      tbuf[ss1 * 138 + xl * 34 + ky * 2] = tre1;
      tbuf[ss1 * 138 + xl * 34 + ky * 2 + 1] = tim1;
    }
    __syncthreads();
    {
      const int xl2 = tid >> 7, y = tid & 127;
      const int p = (xb * 4 + xl2) * 128 + y;
      const int ssel = lu[p];
      const float rres = refb[(size_t)ssel * 64 * 16384 + p];  // residual gather
      const float* tb = tbuf + ssel * 138 + xl2 * 34;
      const float2 stpy = tab[y];
      float acc = 0.f, c0 = 1.f, s0 = 0.f;
#pragma unroll
      for (int k2 = 0; k2 < 16; ++k2) {
        const float tre = tb[k2 * 2], tim = tb[k2 * 2 + 1];
        acc = fmaf(tre, c0, fmaf(-tim, s0, acc));
        float nc = c0 * stpy.x - s0 * stpy.y, ns = s0 * stpy.x + c0 * stpy.y;
        c0 = nc; s0 = ns;
      }
      outb[p] = rres + acc;
    }
    __syncthreads();
  }
}

extern "C" void kernel_launch(void* const* d_in, const int* in_sizes, int n_in,
                              void* d_out, int out_size, void* d_ws, size_t ws_size,
                              hipStream_t stream) {
  const float* ref = (const float*)d_in[0];
  // d_in[1] = physical_coords (unused)
  const int* lu = (const int*)d_in[2];
  const float* w1r = (const float*)d_in[3];
  const float* w1i = (const float*)d_in[4];
  const float* w2r = (const float*)d_in[5];
  const float* w2i = (const float*)d_in[6];
  float* out = (float*)d_out;

  // ws: 4 x 8.39 MB = 33.56 MB (same footprint as round 1)
  unsigned* Xf  = (unsigned*)d_ws;            // [4096 bid][512 m]
  unsigned* Xf2 = Xf  + (size_t)4096 * 512;   // [512 m][4096 bid]
  unsigned* Wt  = Xf2 + (size_t)4096 * 512;   // [512 m][64 o][64 c]
  unsigned* Yf  = Wt  + (size_t)4096 * 512;   // [256 bo][512 m][16 s]

  ktw<<<128, 256, 0, stream>>>(w1r, w1i, w2r, w2i, Wt);
  k1_fwd<<<4096, 256, 0, stream>>>(ref, Xf);
  kt<<<512, 256, 0, stream>>>(Xf, Xf2);
  k2_mix<<<512, 256, 0, stream>>>(Xf2, Wt, Yf);
  k3_inv<<<512, 512, 0, stream>>>(Yf, lu, ref, out);
}